// Round 13
// baseline (401.878 us; speedup 1.0000x reference)
//
#include <hip/hip_runtime.h>
#include <stdint.h>

#define N_NODES 4096
#define K_NN    40
#define B_CLOUDS 8
#define F_IN    8
#define H_DIM   64
#define O_DIM   128

#define OUT_FEAT_ELEMS (B_CLOUDS * N_NODES * O_DIM)   // 4194304
#define EDGES          (B_CLOUDS * N_NODES * K_NN)    // 1310720

typedef short bf16x8 __attribute__((ext_vector_type(8)));
typedef float f32x4  __attribute__((ext_vector_type(4)));

__device__ __forceinline__ unsigned short f2bf(float f) {
    unsigned u = __float_as_uint(f);
    unsigned r = (u + 0x7FFFu + ((u >> 16) & 1u)) >> 16;   // RNE
    return (unsigned short)r;
}

// ---------------------------------------------------------------------------
// Kernel P: precompute W2 bf16 B-fragments into d_ws — UNCHANGED from R10.
// ws[((nt*2+kt)*64+lane)*8+j] = bf16(W2[kt*32+(lane>>4)*8+j][nt*16+(lane&15)])
// ---------------------------------------------------------------------------
__global__ __launch_bounds__(256) void w2prep_kernel(const float* __restrict__ W2,
                                                     unsigned short* __restrict__ ws)
{
    const int idx = blockIdx.x * 256 + threadIdx.x;   // 0..8191
    const int j    = idx & 7;
    const int lane = (idx >> 3) & 63;
    const int kt   = (idx >> 9) & 1;
    const int nt   = idx >> 10;
    const int k = kt * 32 + (lane >> 4) * 8 + j;
    const int n = nt * 16 + (lane & 15);
    ws[idx] = f2bf(W2[k * O_DIM + n]);
}

// ---------------------------------------------------------------------------
// Fused kernel: exact KNN (R10 dataflow, 236 us proven) + PointConv MLP.
// 1024 threads = 16 waves = 16 targets; one wave per target end-to-end.
//
// Phase K (knn): pos SoA in 48 KB LDS; sorted-insertion top-40 (R/P regs).
// Phase G (gather): lane n reads neighbor index straight from its own P reg
//   (no global edge round-trip); message row = [x_j(8) | rel(3)] in VGPRs,
//   rel from the still-live pos LDS.
// -- barrier: pos LDS dead -> ALIASED as Hh[8][48*HSTR] (55.3 KB block) --
// Phase C (conv): two rounds (waves 0-7, then 8-15) since only 8 Hh regions
//   fit. Layer1: readlane-broadcast of row regs (lane = hidden ch) -> Hh
//   bf16. Layer2: 48x v_mfma_f32_16x16x32_bf16, W2 B-frags from d_ws
//   (L1-hot), max over 48 rows (pads = self dups), + b2, store.
// LDS 55296 B -> 2 blocks/CU = 32 waves/CU; __launch_bounds__(1024,8) pins
// VGPR <= 64 to keep that residency.
// ---------------------------------------------------------------------------
#define HSTR 72   // bf16 row stride: 144 B, 16B-aligned rows, 2-way bank (free)

__global__ __launch_bounds__(1024, 8) void fused_kernel(
    const float* __restrict__ pos, const float* __restrict__ x,
    const float* __restrict__ W1, const float* __restrict__ b1,
    const unsigned short* __restrict__ w2f, const float* __restrict__ b2,
    float* __restrict__ out)
{
    __shared__ __align__(16) unsigned char smem[8 * 48 * HSTR * 2];  // 55296 B

    float* px = (float*)smem;          // pos SoA view (phase K/G)
    float* py = px + N_NODES;
    float* pz = py + N_NODES;

    const int b  = blockIdx.x >> 8;           // 256 blocks per cloud
    const int i0 = (blockIdx.x & 255) << 4;   // 16 targets per block
    const float* posb = pos + (size_t)b * N_NODES * 3;

    for (int t = threadIdx.x; t < N_NODES * 3; t += 1024) {
        float v = posb[t];
        int node = t / 3;
        int c = t - node * 3;
        if (c == 0) px[node] = v;
        else if (c == 1) py[node] = v;
        else pz[node] = v;
    }
    __syncthreads();

    const int wave = threadIdx.x >> 6;
    const int lane = threadIdx.x & 63;
    const int i = i0 + wave;
    const int ci = i >> 6;        // chunk containing self
    const int li = i & 63;        // lane of self within that chunk
    const int up_addr = ((lane + 1) & 63) << 2;   // ds_permute dest addr

    const float pix = px[i], piy = py[i], piz = pz[i];

    unsigned R = 0xFFFFFFFFu;   // sorted-ascending d2 bits across lanes
    unsigned P = 0xFFFFFFFFu;   // neighbor index payload

    for (int c = 0; c < 64; ++c) {
        const int j = (c << 6) | lane;
        // bitwise-exact fp32: ((dx*dx + dy*dy) + dz*dz), no FMA contraction
        float dx = __fsub_rn(pix, px[j]);
        float dy = __fsub_rn(piy, py[j]);
        float dz = __fsub_rn(piz, pz[j]);
        float d2 = __fadd_rn(__fadd_rn(__fmul_rn(dx, dx), __fmul_rn(dy, dy)),
                             __fmul_rn(dz, dz));
        unsigned d2b = __float_as_uint(d2);
        if (c == ci)                       // wave-uniform: 1 of 64 chunks
            d2b = (lane == li) ? 0xFFFFFFFFu : d2b;   // loop=False: no self

        const unsigned r39 = (unsigned)__builtin_amdgcn_readlane((int)R, 39);
        unsigned long long mask = __ballot(d2b < r39);
        while (mask) {
            const int src = (int)__builtin_ctzll(mask);
            mask &= mask - 1;
            const unsigned kb = (unsigned)__builtin_amdgcn_readlane((int)d2b, src);
            const unsigned jj = (unsigned)((c << 6) | src);
            const bool keep = (R <= kb);              // captured BEFORE updates
            unsigned long long le = __ballot(keep);
            const int p = (int)__builtin_popcountll(le);
            unsigned upR = (unsigned)__builtin_amdgcn_ds_permute(up_addr, (int)R);
            unsigned upP = (unsigned)__builtin_amdgcn_ds_permute(up_addr, (int)P);
            R = keep ? R : upR;
            P = keep ? P : upP;
            const bool at = (lane == p);
            R = at ? kb : R;
            P = at ? jj : P;
        }
    }

    // ---- emit edges (indices as floats) ----
    float* src_out = out + OUT_FEAT_ELEMS;
    float* tgt_out = src_out + EDGES;
    const int gi = b * N_NODES + i;
    if (lane < K_NN) {
        src_out[(size_t)gi * K_NN + lane] = (float)(b * N_NODES + (int)P);
        tgt_out[(size_t)gi * K_NN + lane] = (float)gi;
    }

    // ---- phase G: gather message row from P regs while pos LDS is live ----
    const int j = (lane < K_NN) ? (int)P : i;   // lanes 40..63: self row (dups)
    const float* xr = x + ((size_t)b * N_NODES + j) * F_IN;
    float4 xa = *(const float4*)xr;
    float4 xb = *(const float4*)(xr + 4);
    float row[11];
    row[0] = xa.x; row[1] = xa.y; row[2] = xa.z; row[3] = xa.w;
    row[4] = xb.x; row[5] = xb.y; row[6] = xb.z; row[7] = xb.w;
    row[8]  = px[j] - pix;
    row[9]  = py[j] - piy;
    row[10] = pz[j] - piz;

    float w1r[11];
#pragma unroll
    for (int f = 0; f < 11; ++f) w1r[f] = W1[f * H_DIM + lane];
    const float b1r = b1[lane];

    __syncthreads();   // all waves done with pos LDS -> alias as Hh

    // ---- phase C: conv in two wave-rounds over 8 Hh regions ----
    unsigned short* HhBase = (unsigned short*)smem;
    const int quad = lane >> 4;
    const int col  = lane & 15;
    const bf16x8* Bws = (const bf16x8*)w2f;

    for (int round = 0; round < 2; ++round) {
        if ((wave >> 3) == round) {
            unsigned short* Hw = HhBase + (wave & 7) * (48 * HSTR);

            // layer 1: broadcast lane n's row regs; lane = hidden channel
            float h = 0.0f;
#pragma unroll
            for (int n = 0; n <= K_NN; ++n) {
                h = b1r;
#pragma unroll
                for (int f = 0; f < 11; ++f) {
                    float mv = __uint_as_float((unsigned)
                        __builtin_amdgcn_readlane((int)__float_as_uint(row[f]), n));
                    h = fmaf(mv, w1r[f], h);
                }
                h = fmaxf(h, 0.0f);
                Hw[n * HSTR + lane] = f2bf(h);
            }
            {   // pad rows 41..47 with self row (n=40); max-invariant
                unsigned short hb = f2bf(h);
#pragma unroll
                for (int r = K_NN + 1; r < 48; ++r) Hw[r * HSTR + lane] = hb;
            }

            // layer 2: MFMA (same-wave ds_write->ds_read ordered by lgkmcnt)
            bf16x8 Af[3][2];
#pragma unroll
            for (int mt = 0; mt < 3; ++mt)
#pragma unroll
                for (int kt = 0; kt < 2; ++kt)
                    Af[mt][kt] = *(const bf16x8*)&Hw[(mt * 16 + col) * HSTR
                                                     + kt * 32 + quad * 8];
#pragma unroll
            for (int nt = 0; nt < 8; ++nt) {
                bf16x8 B0 = Bws[nt * 128 + lane];
                bf16x8 B1 = Bws[nt * 128 + 64 + lane];

                f32x4 c0 = {0.f, 0.f, 0.f, 0.f};
                f32x4 c1 = {0.f, 0.f, 0.f, 0.f};
                f32x4 c2 = {0.f, 0.f, 0.f, 0.f};
                c0 = __builtin_amdgcn_mfma_f32_16x16x32_bf16(Af[0][0], B0, c0, 0, 0, 0);
                c1 = __builtin_amdgcn_mfma_f32_16x16x32_bf16(Af[1][0], B0, c1, 0, 0, 0);
                c2 = __builtin_amdgcn_mfma_f32_16x16x32_bf16(Af[2][0], B0, c2, 0, 0, 0);
                c0 = __builtin_amdgcn_mfma_f32_16x16x32_bf16(Af[0][1], B1, c0, 0, 0, 0);
                c1 = __builtin_amdgcn_mfma_f32_16x16x32_bf16(Af[1][1], B1, c1, 0, 0, 0);
                c2 = __builtin_amdgcn_mfma_f32_16x16x32_bf16(Af[2][1], B1, c2, 0, 0, 0);

                float vm = c0[0];
                vm = fmaxf(vm, c0[1]); vm = fmaxf(vm, c0[2]); vm = fmaxf(vm, c0[3]);
                vm = fmaxf(vm, c1[0]); vm = fmaxf(vm, c1[1]); vm = fmaxf(vm, c1[2]); vm = fmaxf(vm, c1[3]);
                vm = fmaxf(vm, c2[0]); vm = fmaxf(vm, c2[1]); vm = fmaxf(vm, c2[2]); vm = fmaxf(vm, c2[3]);
                vm = fmaxf(vm, __shfl_xor(vm, 16));
                vm = fmaxf(vm, __shfl_xor(vm, 32));
                vm += b2[nt * 16 + col];

                if (lane < 16) out[(size_t)gi * O_DIM + nt * 16 + lane] = vm;
            }
        }
        __syncthreads();   // round-0 LDS reads complete before round-1 writes
    }
}

// ---------------------------------------------------------------------------
extern "C" void kernel_launch(void* const* d_in, const int* in_sizes, int n_in,
                              void* d_out, int out_size, void* d_ws, size_t ws_size,
                              hipStream_t stream) {
    const float* x   = (const float*)d_in[0];
    const float* pos = (const float*)d_in[1];
    const float* W1  = (const float*)d_in[2];
    const float* b1  = (const float*)d_in[3];
    const float* W2  = (const float*)d_in[4];
    const float* b2  = (const float*)d_in[5];
    float* out = (float*)d_out;
    unsigned short* w2f = (unsigned short*)d_ws;   // 8192 bf16 = 16 KB

    w2prep_kernel<<<32, 256, 0, stream>>>(W2, w2f);
    fused_kernel<<<(B_CLOUDS * N_NODES) / 16, 1024, 0, stream>>>(
        pos, x, W1, b1, w2f, b2, out);
}

// Round 14
// 326.184 us; speedup vs baseline: 1.2321x; 1.2321x over previous
//
#include <hip/hip_runtime.h>
#include <stdint.h>

#define N_NODES 4096
#define K_NN    40
#define B_CLOUDS 8
#define F_IN    8
#define H_DIM   64
#define O_DIM   128

#define OUT_FEAT_ELEMS (B_CLOUDS * N_NODES * O_DIM)   // 4194304
#define EDGES          (B_CLOUDS * N_NODES * K_NN)    // 1310720

typedef short bf16x8 __attribute__((ext_vector_type(8)));
typedef float f32x4  __attribute__((ext_vector_type(4)));

__device__ __forceinline__ unsigned short f2bf(float f) {
    unsigned u = __float_as_uint(f);
    unsigned r = (u + 0x7FFFu + ((u >> 16) & 1u)) >> 16;   // RNE
    return (unsigned short)r;
}

// ---------------------------------------------------------------------------
// Kernel A: exact KNN — EXACT R10 version (236 us, proven).
// ---------------------------------------------------------------------------
__global__ __launch_bounds__(1024) void knn_kernel(const float* __restrict__ pos,
                                                   float* __restrict__ out)
{
    __shared__ float px[N_NODES];
    __shared__ float py[N_NODES];
    __shared__ float pz[N_NODES];

    const int b  = blockIdx.x >> 8;           // 256 blocks per cloud
    const int i0 = (blockIdx.x & 255) << 4;   // 16 targets per block
    const float* posb = pos + (size_t)b * N_NODES * 3;

    for (int t = threadIdx.x; t < N_NODES * 3; t += 1024) {
        float v = posb[t];
        int node = t / 3;
        int c = t - node * 3;
        if (c == 0) px[node] = v;
        else if (c == 1) py[node] = v;
        else pz[node] = v;
    }
    __syncthreads();

    const int wave = threadIdx.x >> 6;
    const int lane = threadIdx.x & 63;
    const int i = i0 + wave;
    const int ci = i >> 6;        // chunk containing self
    const int li = i & 63;        // lane of self within that chunk
    const int up_addr = ((lane + 1) & 63) << 2;   // ds_permute dest addr

    const float pix = px[i], piy = py[i], piz = pz[i];

    unsigned R = 0xFFFFFFFFu;   // sorted-ascending d2 bits across lanes
    unsigned P = 0xFFFFFFFFu;   // neighbor index payload

    for (int c = 0; c < 64; ++c) {
        const int j = (c << 6) | lane;
        float dx = __fsub_rn(pix, px[j]);
        float dy = __fsub_rn(piy, py[j]);
        float dz = __fsub_rn(piz, pz[j]);
        float d2 = __fadd_rn(__fadd_rn(__fmul_rn(dx, dx), __fmul_rn(dy, dy)),
                             __fmul_rn(dz, dz));
        unsigned d2b = __float_as_uint(d2);
        if (c == ci)
            d2b = (lane == li) ? 0xFFFFFFFFu : d2b;   // loop=False: no self

        const unsigned r39 = (unsigned)__builtin_amdgcn_readlane((int)R, 39);
        unsigned long long mask = __ballot(d2b < r39);
        while (mask) {
            const int src = (int)__builtin_ctzll(mask);
            mask &= mask - 1;
            const unsigned kb = (unsigned)__builtin_amdgcn_readlane((int)d2b, src);
            const unsigned jj = (unsigned)((c << 6) | src);
            const bool keep = (R <= kb);
            unsigned long long le = __ballot(keep);
            const int p = (int)__builtin_popcountll(le);
            unsigned upR = (unsigned)__builtin_amdgcn_ds_permute(up_addr, (int)R);
            unsigned upP = (unsigned)__builtin_amdgcn_ds_permute(up_addr, (int)P);
            R = keep ? R : upR;
            P = keep ? P : upP;
            const bool at = (lane == p);
            R = at ? kb : R;
            P = at ? jj : P;
        }
    }

    float* src_out = out + OUT_FEAT_ELEMS;
    float* tgt_out = src_out + EDGES;
    const int gi = b * N_NODES + i;
    if (lane < K_NN) {
        src_out[(size_t)gi * K_NN + lane] = (float)(b * N_NODES + (int)P);
        tgt_out[(size_t)gi * K_NN + lane] = (float)gi;
    }
}

// ---------------------------------------------------------------------------
// Kernel P: precompute W2 and W1 bf16 B-fragments into d_ws.
// w2f (offset 0, 8192 bf16): ws[((nt*2+kt)*64+lane)*8+j]
//     = bf16(W2[kt*32+(lane>>4)*8+j][nt*16+(lane&15)])        (R10, proven)
// w1f (offset 8192, 2048 bf16): w1f[(nt*64+lane)*8+j]
//     = k<11 ? bf16(W1[k][nt*16+(lane&15)]) : 0,  k=(lane>>4)*8+j
// ---------------------------------------------------------------------------
__global__ __launch_bounds__(256) void prep_kernel(const float* __restrict__ W2,
                                                   const float* __restrict__ W1,
                                                   unsigned short* __restrict__ ws)
{
    const int idx = blockIdx.x * 256 + threadIdx.x;   // 0..10239
    if (idx < 8192) {
        const int j    = idx & 7;
        const int lane = (idx >> 3) & 63;
        const int kt   = (idx >> 9) & 1;
        const int nt   = idx >> 10;
        const int k = kt * 32 + (lane >> 4) * 8 + j;
        const int n = nt * 16 + (lane & 15);
        ws[idx] = f2bf(W2[k * O_DIM + n]);
    } else if (idx < 8192 + 2048) {
        const int t = idx - 8192;
        const int j    = t & 7;
        const int lane = (t >> 3) & 63;
        const int nt   = t >> 9;          // 0..3
        const int k = (lane >> 4) * 8 + j;          // 0..31
        const int n = nt * 16 + (lane & 15);        // hidden channel
        ws[idx] = (k < 11) ? f2bf(W1[k * H_DIM + n]) : (unsigned short)0;
    }
}

// ---------------------------------------------------------------------------
// Kernel B: per-edge MLP v4 — BOTH layers via MFMA.
// One wave per target. Per-wave private LDS region (48*HSTR bf16 = 6912 B):
//   stage msg[48 rows][k 0..31 bf16, stride 40] (3840 B head of region) ->
//   layer1: H[48x64] = msg[48x32] x W1[32x64] = 12 mfma_16x16x32_bf16,
//   bias in accumulator init, relu on D regs -> overwrite region as
//   Hh[48 rows][64 hidden, stride HSTR] -> layer2: 48 MFMA (R10, proven).
// LDS = 27.6 KB -> 4 blocks/CU; launch_bounds(256,4) caps VGPR at 128.
// ---------------------------------------------------------------------------
#define HSTR 72   // Hh row stride (bf16): 144 B, proven in R10
#define KSTR 40   // msg row stride (bf16): 80 B, 16B-aligned rows

__global__ __launch_bounds__(256, 4) void conv_kernel(
    const float* __restrict__ x, const float* __restrict__ pos,
    const unsigned short* __restrict__ w2f,   // d_ws: w2 frags [0,8192)
    const unsigned short* __restrict__ w1f,   // d_ws: w1 frags [8192,10240)
    const float* __restrict__ b1, const float* __restrict__ b2,
    float* __restrict__ out)
{
    __shared__ __align__(16) unsigned short Hh[4][48 * HSTR];    // 27648 B

    const int b    = blockIdx.x >> 10;
    const int i0   = (blockIdx.x & 1023) << 2;
    const int wave = threadIdx.x >> 6;
    const int lane = threadIdx.x & 63;
    const int quad = lane >> 4;
    const int col  = lane & 15;
    const int i    = i0 + wave;
    const int gi   = b * N_NODES + i;

    unsigned short* Hw = Hh[wave];

    // ---- phase 1: lane n (<48) gathers message row n, stages bf16 to LDS ----
    const float* src_edges = out + OUT_FEAT_ELEMS;
    if (lane < 48) {
        int j;
        if (lane < K_NN) j = (int)src_edges[(size_t)gi * K_NN + lane] - b * N_NODES;
        else             j = i;   // rows 40..47: self row (40 = real self loop,
                                  // 41..47 = pad duplicates; max-invariant)
        const float* xr = x + ((size_t)b * N_NODES + j) * F_IN;
        float4 xa = *(const float4*)xr;
        float4 xb = *(const float4*)(xr + 4);
        const float* pj = pos + ((size_t)b * N_NODES + j) * 3;
        const float* pi = pos + ((size_t)b * N_NODES + i) * 3;
        // pack 11 bf16 + 21 zeros into 16 u32 words, 4x b128 stores
        unsigned w[16];
#pragma unroll
        for (int t = 0; t < 16; ++t) w[t] = 0;
        w[0] = (unsigned)f2bf(xa.x) | ((unsigned)f2bf(xa.y) << 16);
        w[1] = (unsigned)f2bf(xa.z) | ((unsigned)f2bf(xa.w) << 16);
        w[2] = (unsigned)f2bf(xb.x) | ((unsigned)f2bf(xb.y) << 16);
        w[3] = (unsigned)f2bf(xb.z) | ((unsigned)f2bf(xb.w) << 16);
        w[4] = (unsigned)f2bf(pj[0] - pi[0]) | ((unsigned)f2bf(pj[1] - pi[1]) << 16);
        w[5] = (unsigned)f2bf(pj[2] - pi[2]);
        unsigned* mrow = (unsigned*)(Hw + lane * KSTR);   // 80B stride, 16B-aligned
        *(uint4*)(mrow)      = make_uint4(w[0], w[1], w[2], w[3]);
        *(uint4*)(mrow + 4)  = make_uint4(w[4], w[5], w[6], w[7]);
        *(uint4*)(mrow + 8)  = make_uint4(w[8], w[9], w[10], w[11]);
        *(uint4*)(mrow + 12) = make_uint4(w[12], w[13], w[14], w[15]);
    }
    // same-wave ds_write -> ds_read: ordered by lgkmcnt, no barrier needed

    // ---- layer 1 via MFMA: H[48x64] = msg[48x32] . W1[32x64] ----
    bf16x8 Am[3];
#pragma unroll
    for (int mt = 0; mt < 3; ++mt)
        Am[mt] = *(const bf16x8*)&Hw[(mt * 16 + col) * KSTR + quad * 8];

    const bf16x8* W1f = (const bf16x8*)w1f;
    float hreg[12][4];                 // H rows (mt,quad*4+r) for col nt*16+col
#pragma unroll
    for (int nt = 0; nt < 4; ++nt) {
        bf16x8 Bn = W1f[nt * 64 + lane];
        const float bias = b1[nt * 16 + col];
        f32x4 d0 = {bias, bias, bias, bias};
        f32x4 d1 = d0, d2 = d0;
        d0 = __builtin_amdgcn_mfma_f32_16x16x32_bf16(Am[0], Bn, d0, 0, 0, 0);
        d1 = __builtin_amdgcn_mfma_f32_16x16x32_bf16(Am[1], Bn, d1, 0, 0, 0);
        d2 = __builtin_amdgcn_mfma_f32_16x16x32_bf16(Am[2], Bn, d2, 0, 0, 0);
#pragma unroll
        for (int r = 0; r < 4; ++r) {
            hreg[0 * 4 + 0][0] = 0;   // (placeholder no-op, removed by compiler)
            hreg[nt * 3 + 0][r] = fmaxf(d0[r], 0.0f);
            hreg[nt * 3 + 1][r] = fmaxf(d1[r], 0.0f);
            hreg[nt * 3 + 2][r] = fmaxf(d2[r], 0.0f);
        }
    }

    // msg fully consumed -> overwrite region as Hh[row][hidden]
#pragma unroll
    for (int nt = 0; nt < 4; ++nt)
#pragma unroll
        for (int mt = 0; mt < 3; ++mt)
#pragma unroll
            for (int r = 0; r < 4; ++r)
                Hw[(mt * 16 + quad * 4 + r) * HSTR + nt * 16 + col] =
                    f2bf(hreg[nt * 3 + mt][r]);

    // ---- layer 2 via MFMA (R10, proven) ----
    bf16x8 Af[3][2];
#pragma unroll
    for (int mt = 0; mt < 3; ++mt)
#pragma unroll
        for (int kt = 0; kt < 2; ++kt)
            Af[mt][kt] = *(const bf16x8*)&Hw[(mt * 16 + col) * HSTR + kt * 32 + quad * 8];

    const bf16x8* Bws = (const bf16x8*)w2f;
#pragma unroll
    for (int nt = 0; nt < 8; ++nt) {
        bf16x8 B0 = Bws[nt * 128 + lane];
        bf16x8 B1 = Bws[nt * 128 + 64 + lane];

        f32x4 c0 = {0.f, 0.f, 0.f, 0.f};
        f32x4 c1 = {0.f, 0.f, 0.f, 0.f};
        f32x4 c2 = {0.f, 0.f, 0.f, 0.f};
        c0 = __builtin_amdgcn_mfma_f32_16x16x32_bf16(Af[0][0], B0, c0, 0, 0, 0);
        c1 = __builtin_amdgcn_mfma_f32_16x16x32_bf16(Af[1][0], B0, c1, 0, 0, 0);
        c2 = __builtin_amdgcn_mfma_f32_16x16x32_bf16(Af[2][0], B0, c2, 0, 0, 0);
        c0 = __builtin_amdgcn_mfma_f32_16x16x32_bf16(Af[0][1], B1, c0, 0, 0, 0);
        c1 = __builtin_amdgcn_mfma_f32_16x16x32_bf16(Af[1][1], B1, c1, 0, 0, 0);
        c2 = __builtin_amdgcn_mfma_f32_16x16x32_bf16(Af[2][1], B1, c2, 0, 0, 0);

        float vm = c0[0];
        vm = fmaxf(vm, c0[1]); vm = fmaxf(vm, c0[2]); vm = fmaxf(vm, c0[3]);
        vm = fmaxf(vm, c1[0]); vm = fmaxf(vm, c1[1]); vm = fmaxf(vm, c1[2]); vm = fmaxf(vm, c1[3]);
        vm = fmaxf(vm, c2[0]); vm = fmaxf(vm, c2[1]); vm = fmaxf(vm, c2[2]); vm = fmaxf(vm, c2[3]);
        vm = fmaxf(vm, __shfl_xor(vm, 16));
        vm = fmaxf(vm, __shfl_xor(vm, 32));
        vm += b2[nt * 16 + col];

        if (lane < 16) out[(size_t)gi * O_DIM + nt * 16 + lane] = vm;
    }
}

// ---------------------------------------------------------------------------
extern "C" void kernel_launch(void* const* d_in, const int* in_sizes, int n_in,
                              void* d_out, int out_size, void* d_ws, size_t ws_size,
                              hipStream_t stream) {
    const float* x   = (const float*)d_in[0];
    const float* pos = (const float*)d_in[1];
    const float* W1  = (const float*)d_in[2];
    const float* b1  = (const float*)d_in[3];
    const float* W2  = (const float*)d_in[4];
    const float* b2  = (const float*)d_in[5];
    float* out = (float*)d_out;
    unsigned short* ws = (unsigned short*)d_ws;   // 10240 bf16 = 20.5 KB

    prep_kernel<<<40, 256, 0, stream>>>(W2, W1, ws);
    knn_kernel<<<(B_CLOUDS * N_NODES) / 16, 1024, 0, stream>>>(pos, out);
    conv_kernel<<<(B_CLOUDS * N_NODES) / 4, 256, 0, stream>>>(
        x, pos, ws, ws + 8192, b1, b2, out);
}

// Round 15
// 324.546 us; speedup vs baseline: 1.2383x; 1.0050x over previous
//
#include <hip/hip_runtime.h>
#include <stdint.h>

#define N_NODES 4096
#define K_NN    40
#define B_CLOUDS 8
#define F_IN    8
#define H_DIM   64
#define O_DIM   128

#define OUT_FEAT_ELEMS (B_CLOUDS * N_NODES * O_DIM)   // 4194304
#define EDGES          (B_CLOUDS * N_NODES * K_NN)    // 1310720

typedef short bf16x8 __attribute__((ext_vector_type(8)));
typedef float f32x4  __attribute__((ext_vector_type(4)));

__device__ __forceinline__ unsigned short f2bf(float f) {
    unsigned u = __float_as_uint(f);
    unsigned r = (u + 0x7FFFu + ((u >> 16) & 1u)) >> 16;   // RNE
    return (unsigned short)r;
}

// ---------------------------------------------------------------------------
// Kernel A: exact KNN v2 — sentinel + select/max ordered insert.
//
// Keys are u64 (d2_f32_bits << 32) | j: u64 ascending == (d2, idx) ascending
// (d2 >= 0 so f32-bit order == u32 order). Array RP sorted ascending across
// lanes; lane 0 holds a permanent 0-sentinel so every insert rank p >= 1.
// Insert of wave-uniform kbjj:
//   keep = RP <= kbjj  (prefix; lane 0 always keeps)
//   up   = RP shifted up one lane (ds_bpermute pull from lane-1)
//   RP   = keep ? RP : max64(kbjj, up)
// -- at lane p: up = RP[p-1] <= kbjj -> max = kbjj (deposit); above: up wins.
// No rank popcount, no writelane, no separate payload registers.
// Self is masked to hi=FFFFFFFF (sorts after all 4095 real keys -> never in
// lanes 1..40). Stale-qualified candidates land at rank >= 41 (R4 proof).
// Emit: lanes 1..40.
// ---------------------------------------------------------------------------
__global__ __launch_bounds__(1024) void knn_kernel(const float* __restrict__ pos,
                                                   float* __restrict__ out)
{
    __shared__ float px[N_NODES];
    __shared__ float py[N_NODES];
    __shared__ float pz[N_NODES];

    const int b  = blockIdx.x >> 8;           // 256 blocks per cloud
    const int i0 = (blockIdx.x & 255) << 4;   // 16 targets per block
    const float* posb = pos + (size_t)b * N_NODES * 3;

    for (int t = threadIdx.x; t < N_NODES * 3; t += 1024) {
        float v = posb[t];
        int node = t / 3;
        int c = t - node * 3;
        if (c == 0) px[node] = v;
        else if (c == 1) py[node] = v;
        else pz[node] = v;
    }
    __syncthreads();

    const int wave = threadIdx.x >> 6;
    const int lane = threadIdx.x & 63;
    const int i = i0 + wave;
    const int ci = i >> 6;        // chunk containing self
    const int li = i & 63;        // lane of self within that chunk
    const int dn_addr = ((lane + 63) & 63) << 2;   // bpermute: pull lane-1

    const float pix = px[i], piy = py[i], piz = pz[i];

    // sorted-ascending u64 keys; lane 0 = 0-sentinel
    unsigned Rhi = (lane == 0) ? 0u : 0xFFFFFFFFu;   // d2 bits
    unsigned Rlo = (lane == 0) ? 0u : 0xFFFFFFFFu;   // index payload

    for (int c = 0; c < 64; ++c) {
        const int j = (c << 6) | lane;
        // bitwise-exact fp32: ((dx*dx + dy*dy) + dz*dz), no FMA contraction
        float dx = __fsub_rn(pix, px[j]);
        float dy = __fsub_rn(piy, py[j]);
        float dz = __fsub_rn(piz, pz[j]);
        float d2 = __fadd_rn(__fadd_rn(__fmul_rn(dx, dx), __fmul_rn(dy, dy)),
                             __fmul_rn(dz, dz));
        unsigned d2b = __float_as_uint(d2);
        if (c == ci)                       // wave-uniform: 1 of 64 chunks
            d2b = (lane == li) ? 0xFFFFFFFFu : d2b;   // self: sorts after all real

        // threshold = 40th-smallest real key (lane 40; lane 0 is sentinel)
        const unsigned r40hi = (unsigned)__builtin_amdgcn_readlane((int)Rhi, 40);
        const unsigned r40lo = (unsigned)__builtin_amdgcn_readlane((int)Rlo, 40);
        const unsigned long long r40 = ((unsigned long long)r40hi << 32) | r40lo;
        const unsigned long long key = ((unsigned long long)d2b << 32) | (unsigned)j;

        unsigned long long mask = __ballot(key < r40);
        while (mask) {
            const int src = (int)__builtin_ctzll(mask);
            mask &= mask - 1;
            const unsigned long long kbjj =
                ((unsigned long long)(unsigned)__builtin_amdgcn_readlane((int)d2b, src) << 32)
                | (unsigned)((c << 6) | src);
            const unsigned long long RP = ((unsigned long long)Rhi << 32) | Rlo;
            const bool keep = (RP <= kbjj);           // prefix; lane 0 always
            const unsigned uplo = (unsigned)__builtin_amdgcn_ds_bpermute(dn_addr, (int)Rlo);
            const unsigned uphi = (unsigned)__builtin_amdgcn_ds_bpermute(dn_addr, (int)Rhi);
            const unsigned long long up = ((unsigned long long)uphi << 32) | uplo;
            const unsigned long long mx = (up > kbjj) ? up : kbjj;
            const unsigned long long nw = keep ? RP : mx;
            Rhi = (unsigned)(nw >> 32);
            Rlo = (unsigned)nw;
        }
    }

    // Emit edges from lanes 1..40: src = global neighbor id, tgt = target id
    float* src_out = out + OUT_FEAT_ELEMS;
    float* tgt_out = src_out + EDGES;
    const int gi = b * N_NODES + i;
    const unsigned el = (unsigned)(lane - 1);
    if (el < K_NN) {
        src_out[(size_t)gi * K_NN + el] = (float)(b * N_NODES + (int)Rlo);
        tgt_out[(size_t)gi * K_NN + el] = (float)gi;
    }
}

// ---------------------------------------------------------------------------
// Kernel P: precompute W2 and W1 bf16 B-fragments into d_ws — R14, proven.
// ---------------------------------------------------------------------------
__global__ __launch_bounds__(256) void prep_kernel(const float* __restrict__ W2,
                                                   const float* __restrict__ W1,
                                                   unsigned short* __restrict__ ws)
{
    const int idx = blockIdx.x * 256 + threadIdx.x;   // 0..10239
    if (idx < 8192) {
        const int j    = idx & 7;
        const int lane = (idx >> 3) & 63;
        const int kt   = (idx >> 9) & 1;
        const int nt   = idx >> 10;
        const int k = kt * 32 + (lane >> 4) * 8 + j;
        const int n = nt * 16 + (lane & 15);
        ws[idx] = f2bf(W2[k * O_DIM + n]);
    } else if (idx < 8192 + 2048) {
        const int t = idx - 8192;
        const int j    = t & 7;
        const int lane = (t >> 3) & 63;
        const int nt   = t >> 9;          // 0..3
        const int k = (lane >> 4) * 8 + j;          // 0..31
        const int n = nt * 16 + (lane & 15);        // hidden channel
        ws[idx] = (k < 11) ? f2bf(W1[k * H_DIM + n]) : (unsigned short)0;
    }
}

// ---------------------------------------------------------------------------
// Kernel B: per-edge MLP, both layers MFMA — UNCHANGED from R14 (proven).
// ---------------------------------------------------------------------------
#define HSTR 72   // Hh row stride (bf16): 144 B
#define KSTR 40   // msg row stride (bf16): 80 B, 16B-aligned rows

__global__ __launch_bounds__(256, 4) void conv_kernel(
    const float* __restrict__ x, const float* __restrict__ pos,
    const unsigned short* __restrict__ w2f,   // d_ws: w2 frags [0,8192)
    const unsigned short* __restrict__ w1f,   // d_ws: w1 frags [8192,10240)
    const float* __restrict__ b1, const float* __restrict__ b2,
    float* __restrict__ out)
{
    __shared__ __align__(16) unsigned short Hh[4][48 * HSTR];    // 27648 B

    const int b    = blockIdx.x >> 10;
    const int i0   = (blockIdx.x & 1023) << 2;
    const int wave = threadIdx.x >> 6;
    const int lane = threadIdx.x & 63;
    const int quad = lane >> 4;
    const int col  = lane & 15;
    const int i    = i0 + wave;
    const int gi   = b * N_NODES + i;

    unsigned short* Hw = Hh[wave];

    // ---- phase 1: lane n (<48) gathers message row n, stages bf16 to LDS ----
    const float* src_edges = out + OUT_FEAT_ELEMS;
    if (lane < 48) {
        int j;
        if (lane < K_NN) j = (int)src_edges[(size_t)gi * K_NN + lane] - b * N_NODES;
        else             j = i;   // rows 40..47: self row + pad dups (max-safe)
        const float* xr = x + ((size_t)b * N_NODES + j) * F_IN;
        float4 xa = *(const float4*)xr;
        float4 xb = *(const float4*)(xr + 4);
        const float* pj = pos + ((size_t)b * N_NODES + j) * 3;
        const float* pi = pos + ((size_t)b * N_NODES + i) * 3;
        unsigned w[16];
#pragma unroll
        for (int t = 0; t < 16; ++t) w[t] = 0;
        w[0] = (unsigned)f2bf(xa.x) | ((unsigned)f2bf(xa.y) << 16);
        w[1] = (unsigned)f2bf(xa.z) | ((unsigned)f2bf(xa.w) << 16);
        w[2] = (unsigned)f2bf(xb.x) | ((unsigned)f2bf(xb.y) << 16);
        w[3] = (unsigned)f2bf(xb.z) | ((unsigned)f2bf(xb.w) << 16);
        w[4] = (unsigned)f2bf(pj[0] - pi[0]) | ((unsigned)f2bf(pj[1] - pi[1]) << 16);
        w[5] = (unsigned)f2bf(pj[2] - pi[2]);
        unsigned* mrow = (unsigned*)(Hw + lane * KSTR);
        *(uint4*)(mrow)      = make_uint4(w[0], w[1], w[2], w[3]);
        *(uint4*)(mrow + 4)  = make_uint4(w[4], w[5], w[6], w[7]);
        *(uint4*)(mrow + 8)  = make_uint4(w[8], w[9], w[10], w[11]);
        *(uint4*)(mrow + 12) = make_uint4(w[12], w[13], w[14], w[15]);
    }
    // same-wave ds_write -> ds_read: ordered by lgkmcnt, no barrier needed

    // ---- layer 1 via MFMA: H[48x64] = msg[48x32] . W1[32x64] ----
    bf16x8 Am[3];
#pragma unroll
    for (int mt = 0; mt < 3; ++mt)
        Am[mt] = *(const bf16x8*)&Hw[(mt * 16 + col) * KSTR + quad * 8];

    const bf16x8* W1f = (const bf16x8*)w1f;
    float hreg[12][4];
#pragma unroll
    for (int nt = 0; nt < 4; ++nt) {
        bf16x8 Bn = W1f[nt * 64 + lane];
        const float bias = b1[nt * 16 + col];
        f32x4 d0 = {bias, bias, bias, bias};
        f32x4 d1 = d0, d2 = d0;
        d0 = __builtin_amdgcn_mfma_f32_16x16x32_bf16(Am[0], Bn, d0, 0, 0, 0);
        d1 = __builtin_amdgcn_mfma_f32_16x16x32_bf16(Am[1], Bn, d1, 0, 0, 0);
        d2 = __builtin_amdgcn_mfma_f32_16x16x32_bf16(Am[2], Bn, d2, 0, 0, 0);
#pragma unroll
        for (int r = 0; r < 4; ++r) {
            hreg[nt * 3 + 0][r] = fmaxf(d0[r], 0.0f);
            hreg[nt * 3 + 1][r] = fmaxf(d1[r], 0.0f);
            hreg[nt * 3 + 2][r] = fmaxf(d2[r], 0.0f);
        }
    }

    // msg fully consumed -> overwrite region as Hh[row][hidden]
#pragma unroll
    for (int nt = 0; nt < 4; ++nt)
#pragma unroll
        for (int mt = 0; mt < 3; ++mt)
#pragma unroll
            for (int r = 0; r < 4; ++r)
                Hw[(mt * 16 + quad * 4 + r) * HSTR + nt * 16 + col] =
                    f2bf(hreg[nt * 3 + mt][r]);

    // ---- layer 2 via MFMA ----
    bf16x8 Af[3][2];
#pragma unroll
    for (int mt = 0; mt < 3; ++mt)
#pragma unroll
        for (int kt = 0; kt < 2; ++kt)
            Af[mt][kt] = *(const bf16x8*)&Hw[(mt * 16 + col) * HSTR + kt * 32 + quad * 8];

    const bf16x8* Bws = (const bf16x8*)w2f;
#pragma unroll
    for (int nt = 0; nt < 8; ++nt) {
        bf16x8 B0 = Bws[nt * 128 + lane];
        bf16x8 B1 = Bws[nt * 128 + 64 + lane];

        f32x4 c0 = {0.f, 0.f, 0.f, 0.f};
        f32x4 c1 = {0.f, 0.f, 0.f, 0.f};
        f32x4 c2 = {0.f, 0.f, 0.f, 0.f};
        c0 = __builtin_amdgcn_mfma_f32_16x16x32_bf16(Af[0][0], B0, c0, 0, 0, 0);
        c1 = __builtin_amdgcn_mfma_f32_16x16x32_bf16(Af[1][0], B0, c1, 0, 0, 0);
        c2 = __builtin_amdgcn_mfma_f32_16x16x32_bf16(Af[2][0], B0, c2, 0, 0, 0);
        c0 = __builtin_amdgcn_mfma_f32_16x16x32_bf16(Af[0][1], B1, c0, 0, 0, 0);
        c1 = __builtin_amdgcn_mfma_f32_16x16x32_bf16(Af[1][1], B1, c1, 0, 0, 0);
        c2 = __builtin_amdgcn_mfma_f32_16x16x32_bf16(Af[2][1], B1, c2, 0, 0, 0);

        float vm = c0[0];
        vm = fmaxf(vm, c0[1]); vm = fmaxf(vm, c0[2]); vm = fmaxf(vm, c0[3]);
        vm = fmaxf(vm, c1[0]); vm = fmaxf(vm, c1[1]); vm = fmaxf(vm, c1[2]); vm = fmaxf(vm, c1[3]);
        vm = fmaxf(vm, c2[0]); vm = fmaxf(vm, c2[1]); vm = fmaxf(vm, c2[2]); vm = fmaxf(vm, c2[3]);
        vm = fmaxf(vm, __shfl_xor(vm, 16));
        vm = fmaxf(vm, __shfl_xor(vm, 32));
        vm += b2[nt * 16 + col];

        if (lane < 16) out[(size_t)gi * O_DIM + nt * 16 + lane] = vm;
    }
}

// ---------------------------------------------------------------------------
extern "C" void kernel_launch(void* const* d_in, const int* in_sizes, int n_in,
                              void* d_out, int out_size, void* d_ws, size_t ws_size,
                              hipStream_t stream) {
    const float* x   = (const float*)d_in[0];
    const float* pos = (const float*)d_in[1];
    const float* W1  = (const float*)d_in[2];
    const float* b1  = (const float*)d_in[3];
    const float* W2  = (const float*)d_in[4];
    const float* b2  = (const float*)d_in[5];
    float* out = (float*)d_out;
    unsigned short* ws = (unsigned short*)d_ws;   // 10240 bf16 = 20.5 KB

    prep_kernel<<<40, 256, 0, stream>>>(W2, W1, ws);
    knn_kernel<<<(B_CLOUDS * N_NODES) / 16, 1024, 0, stream>>>(pos, out);
    conv_kernel<<<(B_CLOUDS * N_NODES) / 4, 256, 0, stream>>>(
        x, pos, ws, ws + 8192, b1, b2, out);
}

// Round 16
// 315.317 us; speedup vs baseline: 1.2745x; 1.0293x over previous
//
#include <hip/hip_runtime.h>
#include <stdint.h>

#define N_NODES 4096
#define K_NN    40
#define B_CLOUDS 8
#define F_IN    8
#define H_DIM   64
#define O_DIM   128

#define OUT_FEAT_ELEMS (B_CLOUDS * N_NODES * O_DIM)   // 4194304
#define EDGES          (B_CLOUDS * N_NODES * K_NN)    // 1310720

typedef short bf16x8 __attribute__((ext_vector_type(8)));
typedef float f32x4  __attribute__((ext_vector_type(4)));

__device__ __forceinline__ unsigned short f2bf(float f) {
    unsigned u = __float_as_uint(f);
    unsigned r = (u + 0x7FFFu + ((u >> 16) & 1u)) >> 16;   // RNE
    return (unsigned short)r;
}

// wave_shr:1 — lane i receives lane i-1's value, VALU DPP (no DS round-trip).
// Lane 0 gets 0 (bound_ctrl); harmless: lane 0 sentinel always keeps.
__device__ __forceinline__ unsigned shr1_dpp(unsigned v) {
    return (unsigned)__builtin_amdgcn_update_dpp(0, (int)v, 0x138, 0xF, 0xF, true);
}

// ---------------------------------------------------------------------------
// Kernel A: exact KNN v3 — R15 sentinel/select-max insert, with the shift-up
// moved from ds_bpermute (DS pipe, ~35 cyc) to DPP wave_shr:1 (VALU, ~5 cyc).
// The serial per-insert chain was the bottleneck (VALUBusy is inflated by the
// gfx94x 4-cyc formula; true issue occupancy ~40%, rest = chain stall).
//
// Keys u64 (d2_bits<<32)|j; array ascending across lanes; lane 0 = 0-sentinel
// (every insert rank >= 1). Insert of uniform kbjj:
//   keep = RP <= kbjj;  up = shr1(RP);  RP = keep ? RP : max64(kbjj, up)
// Self masked to hi=FFFFFFFF. Stale-qualified inserts land rank >= 41 (R4
// proof; capacity 63 >= 40). Emit lanes 1..40.
// ---------------------------------------------------------------------------
__global__ __launch_bounds__(1024) void knn_kernel(const float* __restrict__ pos,
                                                   float* __restrict__ out)
{
    __shared__ float px[N_NODES];
    __shared__ float py[N_NODES];
    __shared__ float pz[N_NODES];

    const int b  = blockIdx.x >> 8;           // 256 blocks per cloud
    const int i0 = (blockIdx.x & 255) << 4;   // 16 targets per block
    const float* posb = pos + (size_t)b * N_NODES * 3;

    for (int t = threadIdx.x; t < N_NODES * 3; t += 1024) {
        float v = posb[t];
        int node = t / 3;
        int c = t - node * 3;
        if (c == 0) px[node] = v;
        else if (c == 1) py[node] = v;
        else pz[node] = v;
    }
    __syncthreads();

    const int wave = threadIdx.x >> 6;
    const int lane = threadIdx.x & 63;
    const int i = i0 + wave;
    const int ci = i >> 6;        // chunk containing self
    const int li = i & 63;        // lane of self within that chunk

    const float pix = px[i], piy = py[i], piz = pz[i];

    // sorted-ascending u64 keys; lane 0 = 0-sentinel
    unsigned Rhi = (lane == 0) ? 0u : 0xFFFFFFFFu;   // d2 bits
    unsigned Rlo = (lane == 0) ? 0u : 0xFFFFFFFFu;   // index payload

    for (int c = 0; c < 64; ++c) {
        const int j = (c << 6) | lane;
        // bitwise-exact fp32: ((dx*dx + dy*dy) + dz*dz), no FMA contraction
        float dx = __fsub_rn(pix, px[j]);
        float dy = __fsub_rn(piy, py[j]);
        float dz = __fsub_rn(piz, pz[j]);
        float d2 = __fadd_rn(__fadd_rn(__fmul_rn(dx, dx), __fmul_rn(dy, dy)),
                             __fmul_rn(dz, dz));
        unsigned d2b = __float_as_uint(d2);
        if (c == ci)                       // wave-uniform: 1 of 64 chunks
            d2b = (lane == li) ? 0xFFFFFFFFu : d2b;   // self sorts after all real

        // threshold = 40th-smallest real key (lane 40; lane 0 is sentinel)
        const unsigned r40hi = (unsigned)__builtin_amdgcn_readlane((int)Rhi, 40);
        const unsigned r40lo = (unsigned)__builtin_amdgcn_readlane((int)Rlo, 40);
        const unsigned long long r40 = ((unsigned long long)r40hi << 32) | r40lo;
        const unsigned long long key = ((unsigned long long)d2b << 32) | (unsigned)j;

        unsigned long long mask = __ballot(key < r40);
        while (mask) {
            const int src = (int)__builtin_ctzll(mask);
            mask &= mask - 1;
            const unsigned long long kbjj =
                ((unsigned long long)(unsigned)__builtin_amdgcn_readlane((int)d2b, src) << 32)
                | (unsigned)((c << 6) | src);
            const unsigned long long RP = ((unsigned long long)Rhi << 32) | Rlo;
            const bool keep = (RP <= kbjj);           // prefix; lane 0 always
            const unsigned uplo = shr1_dpp(Rlo);      // VALU DPP shift-up
            const unsigned uphi = shr1_dpp(Rhi);
            const unsigned long long up = ((unsigned long long)uphi << 32) | uplo;
            const unsigned long long mx = (up > kbjj) ? up : kbjj;
            const unsigned long long nw = keep ? RP : mx;
            Rhi = (unsigned)(nw >> 32);
            Rlo = (unsigned)nw;
        }
    }

    // Emit edges from lanes 1..40: src = global neighbor id, tgt = target id
    float* src_out = out + OUT_FEAT_ELEMS;
    float* tgt_out = src_out + EDGES;
    const int gi = b * N_NODES + i;
    const unsigned el = (unsigned)(lane - 1);
    if (el < K_NN) {
        src_out[(size_t)gi * K_NN + el] = (float)(b * N_NODES + (int)Rlo);
        tgt_out[(size_t)gi * K_NN + el] = (float)gi;
    }
}

// ---------------------------------------------------------------------------
// Kernel P: precompute W2 and W1 bf16 B-fragments into d_ws — R14, proven.
// ---------------------------------------------------------------------------
__global__ __launch_bounds__(256) void prep_kernel(const float* __restrict__ W2,
                                                   const float* __restrict__ W1,
                                                   unsigned short* __restrict__ ws)
{
    const int idx = blockIdx.x * 256 + threadIdx.x;   // 0..10239
    if (idx < 8192) {
        const int j    = idx & 7;
        const int lane = (idx >> 3) & 63;
        const int kt   = (idx >> 9) & 1;
        const int nt   = idx >> 10;
        const int k = kt * 32 + (lane >> 4) * 8 + j;
        const int n = nt * 16 + (lane & 15);
        ws[idx] = f2bf(W2[k * O_DIM + n]);
    } else if (idx < 8192 + 2048) {
        const int t = idx - 8192;
        const int j    = t & 7;
        const int lane = (t >> 3) & 63;
        const int nt   = t >> 9;          // 0..3
        const int k = (lane >> 4) * 8 + j;          // 0..31
        const int n = nt * 16 + (lane & 15);        // hidden channel
        ws[idx] = (k < 11) ? f2bf(W1[k * H_DIM + n]) : (unsigned short)0;
    }
}

// ---------------------------------------------------------------------------
// Kernel B: per-edge MLP, both layers MFMA — UNCHANGED from R14 (proven).
// ---------------------------------------------------------------------------
#define HSTR 72   // Hh row stride (bf16): 144 B
#define KSTR 40   // msg row stride (bf16): 80 B, 16B-aligned rows

__global__ __launch_bounds__(256, 4) void conv_kernel(
    const float* __restrict__ x, const float* __restrict__ pos,
    const unsigned short* __restrict__ w2f,   // d_ws: w2 frags [0,8192)
    const unsigned short* __restrict__ w1f,   // d_ws: w1 frags [8192,10240)
    const float* __restrict__ b1, const float* __restrict__ b2,
    float* __restrict__ out)
{
    __shared__ __align__(16) unsigned short Hh[4][48 * HSTR];    // 27648 B

    const int b    = blockIdx.x >> 10;
    const int i0   = (blockIdx.x & 1023) << 2;
    const int wave = threadIdx.x >> 6;
    const int lane = threadIdx.x & 63;
    const int quad = lane >> 4;
    const int col  = lane & 15;
    const int i    = i0 + wave;
    const int gi   = b * N_NODES + i;

    unsigned short* Hw = Hh[wave];

    // ---- phase 1: lane n (<48) gathers message row n, stages bf16 to LDS ----
    const float* src_edges = out + OUT_FEAT_ELEMS;
    if (lane < 48) {
        int j;
        if (lane < K_NN) j = (int)src_edges[(size_t)gi * K_NN + lane] - b * N_NODES;
        else             j = i;   // rows 40..47: self row + pad dups (max-safe)
        const float* xr = x + ((size_t)b * N_NODES + j) * F_IN;
        float4 xa = *(const float4*)xr;
        float4 xb = *(const float4*)(xr + 4);
        const float* pj = pos + ((size_t)b * N_NODES + j) * 3;
        const float* pi = pos + ((size_t)b * N_NODES + i) * 3;
        unsigned w[16];
#pragma unroll
        for (int t = 0; t < 16; ++t) w[t] = 0;
        w[0] = (unsigned)f2bf(xa.x) | ((unsigned)f2bf(xa.y) << 16);
        w[1] = (unsigned)f2bf(xa.z) | ((unsigned)f2bf(xa.w) << 16);
        w[2] = (unsigned)f2bf(xb.x) | ((unsigned)f2bf(xb.y) << 16);
        w[3] = (unsigned)f2bf(xb.z) | ((unsigned)f2bf(xb.w) << 16);
        w[4] = (unsigned)f2bf(pj[0] - pi[0]) | ((unsigned)f2bf(pj[1] - pi[1]) << 16);
        w[5] = (unsigned)f2bf(pj[2] - pi[2]);
        unsigned* mrow = (unsigned*)(Hw + lane * KSTR);
        *(uint4*)(mrow)      = make_uint4(w[0], w[1], w[2], w[3]);
        *(uint4*)(mrow + 4)  = make_uint4(w[4], w[5], w[6], w[7]);
        *(uint4*)(mrow + 8)  = make_uint4(w[8], w[9], w[10], w[11]);
        *(uint4*)(mrow + 12) = make_uint4(w[12], w[13], w[14], w[15]);
    }
    // same-wave ds_write -> ds_read: ordered by lgkmcnt, no barrier needed

    // ---- layer 1 via MFMA: H[48x64] = msg[48x32] . W1[32x64] ----
    bf16x8 Am[3];
#pragma unroll
    for (int mt = 0; mt < 3; ++mt)
        Am[mt] = *(const bf16x8*)&Hw[(mt * 16 + col) * KSTR + quad * 8];

    const bf16x8* W1f = (const bf16x8*)w1f;
    float hreg[12][4];
#pragma unroll
    for (int nt = 0; nt < 4; ++nt) {
        bf16x8 Bn = W1f[nt * 64 + lane];
        const float bias = b1[nt * 16 + col];
        f32x4 d0 = {bias, bias, bias, bias};
        f32x4 d1 = d0, d2 = d0;
        d0 = __builtin_amdgcn_mfma_f32_16x16x32_bf16(Am[0], Bn, d0, 0, 0, 0);
        d1 = __builtin_amdgcn_mfma_f32_16x16x32_bf16(Am[1], Bn, d1, 0, 0, 0);
        d2 = __builtin_amdgcn_mfma_f32_16x16x32_bf16(Am[2], Bn, d2, 0, 0, 0);
#pragma unroll
        for (int r = 0; r < 4; ++r) {
            hreg[nt * 3 + 0][r] = fmaxf(d0[r], 0.0f);
            hreg[nt * 3 + 1][r] = fmaxf(d1[r], 0.0f);
            hreg[nt * 3 + 2][r] = fmaxf(d2[r], 0.0f);
        }
    }

    // msg fully consumed -> overwrite region as Hh[row][hidden]
#pragma unroll
    for (int nt = 0; nt < 4; ++nt)
#pragma unroll
        for (int mt = 0; mt < 3; ++mt)
#pragma unroll
            for (int r = 0; r < 4; ++r)
                Hw[(mt * 16 + quad * 4 + r) * HSTR + nt * 16 + col] =
                    f2bf(hreg[nt * 3 + mt][r]);

    // ---- layer 2 via MFMA ----
    bf16x8 Af[3][2];
#pragma unroll
    for (int mt = 0; mt < 3; ++mt)
#pragma unroll
        for (int kt = 0; kt < 2; ++kt)
            Af[mt][kt] = *(const bf16x8*)&Hw[(mt * 16 + col) * HSTR + kt * 32 + quad * 8];

    const bf16x8* Bws = (const bf16x8*)w2f;
#pragma unroll
    for (int nt = 0; nt < 8; ++nt) {
        bf16x8 B0 = Bws[nt * 128 + lane];
        bf16x8 B1 = Bws[nt * 128 + 64 + lane];

        f32x4 c0 = {0.f, 0.f, 0.f, 0.f};
        f32x4 c1 = {0.f, 0.f, 0.f, 0.f};
        f32x4 c2 = {0.f, 0.f, 0.f, 0.f};
        c0 = __builtin_amdgcn_mfma_f32_16x16x32_bf16(Af[0][0], B0, c0, 0, 0, 0);
        c1 = __builtin_amdgcn_mfma_f32_16x16x32_bf16(Af[1][0], B0, c1, 0, 0, 0);
        c2 = __builtin_amdgcn_mfma_f32_16x16x32_bf16(Af[2][0], B0, c2, 0, 0, 0);
        c0 = __builtin_amdgcn_mfma_f32_16x16x32_bf16(Af[0][1], B1, c0, 0, 0, 0);
        c1 = __builtin_amdgcn_mfma_f32_16x16x32_bf16(Af[1][1], B1, c1, 0, 0, 0);
        c2 = __builtin_amdgcn_mfma_f32_16x16x32_bf16(Af[2][1], B1, c2, 0, 0, 0);

        float vm = c0[0];
        vm = fmaxf(vm, c0[1]); vm = fmaxf(vm, c0[2]); vm = fmaxf(vm, c0[3]);
        vm = fmaxf(vm, c1[0]); vm = fmaxf(vm, c1[1]); vm = fmaxf(vm, c1[2]); vm = fmaxf(vm, c1[3]);
        vm = fmaxf(vm, c2[0]); vm = fmaxf(vm, c2[1]); vm = fmaxf(vm, c2[2]); vm = fmaxf(vm, c2[3]);
        vm = fmaxf(vm, __shfl_xor(vm, 16));
        vm = fmaxf(vm, __shfl_xor(vm, 32));
        vm += b2[nt * 16 + col];

        if (lane < 16) out[(size_t)gi * O_DIM + nt * 16 + lane] = vm;
    }
}

// ---------------------------------------------------------------------------
extern "C" void kernel_launch(void* const* d_in, const int* in_sizes, int n_in,
                              void* d_out, int out_size, void* d_ws, size_t ws_size,
                              hipStream_t stream) {
    const float* x   = (const float*)d_in[0];
    const float* pos = (const float*)d_in[1];
    const float* W1  = (const float*)d_in[2];
    const float* b1  = (const float*)d_in[3];
    const float* W2  = (const float*)d_in[4];
    const float* b2  = (const float*)d_in[5];
    float* out = (float*)d_out;
    unsigned short* ws = (unsigned short*)d_ws;   // 10240 bf16 = 20.5 KB

    prep_kernel<<<40, 256, 0, stream>>>(W2, W1, ws);
    knn_kernel<<<(B_CLOUDS * N_NODES) / 16, 1024, 0, stream>>>(pos, out);
    conv_kernel<<<(B_CLOUDS * N_NODES) / 4, 256, 0, stream>>>(
        x, pos, ws, ws + 8192, b1, b2, out);
}